// Round 11
// baseline (370.387 us; speedup 1.0000x reference)
//
#include <hip/hip_runtime.h>
#include <math.h>

#define BB 32
#define SS 4096
#define DD 1024
#define UU 1024
#define TROWS 4                 // rows per tile (one per wave)
#define CHROWS 128              // rows per block
#define NT (CHROWS / TROWS)     // 32 tiles per block
#define CHB (SS / CHROWS)       // 32 chunks per batch
#define FBLK (BB * CHB)         // 1024 flash blocks
#define GBLK 128                // gauss blocks (u-slices, dispatched first)
#define NPART CHB               // 32 partials per batch (one per block)
#define TARGET (CHB + GBLK)     // 160 arrivals per b

#define LOAD_LDS16(g, l) __builtin_amdgcn_global_load_lds( \
    (const __attribute__((address_space(1))) unsigned int*)(g), \
    (__attribute__((address_space(3))) unsigned int*)(l), 16, 0, 0)

// stage one 16 KB tile (4 rows) into LDS buffer `dst` (all 256 threads)
#define STAGE(ti, dst) do {                                              \
    const char* gt_ = gbase + (size_t)(ti) * 16384;                      \
    char* lb_ = (char*)smem + (dst) * 16384;                             \
    _Pragma("unroll")                                                    \
    for (int j_ = 0; j_ < 4; ++j_)                                       \
        LOAD_LDS16(gt_ + j_ * 4096 + tid * 16, lb_ + j_ * 4096 + tid * 16); \
} while (0)

// ws layout (floats):
//   [0 .. 4096)        gpart: per (b, gauss-block) pre-sigmoid partials (b*128+g)
//   [4096 .. 6144)     (m, l) per flash partial (FBLK*2)
//   [6144 .. 6176)     cnt: per-b arrival counters (ints, memset to 0 each launch)
//   [8192 .. 8192+FBLK*DD)  acc partials (4 MiB)

__device__ __forceinline__ void combine_b(int b, float* smem,
                                          const float* mlbuf, const float* accbuf,
                                          const float* gpart, const float* key_lengths,
                                          const int* win, float* ctx, int tid) {
    float* cm = smem;   // [0..31] m, [32..63] l, [64..191] gpart tree, [192..223] wexp
    if (tid < 32) {
        cm[tid]      = mlbuf[(b * NPART + tid) * 2];
        cm[32 + tid] = mlbuf[(b * NPART + tid) * 2 + 1];
    }
    if (tid >= 64 && tid < 192) cm[tid] = gpart[b * GBLK + (tid - 64)];
    __syncthreads();
    for (int t = 64; t > 0; t >>= 1) {
        if (tid < t) cm[64 + tid] += cm[64 + tid + t];
        __syncthreads();
    }
    float presig = cm[64];
    float M = -INFINITY;
#pragma unroll
    for (int i = 0; i < 32; ++i) M = fmaxf(M, cm[i]);
    float L = 0.f;
#pragma unroll
    for (int i = 0; i < 32; ++i) L += cm[32 + i] * __expf(cm[i] - M);
    if (tid < 32) cm[192 + tid] = __expf(cm[tid] - M);
    __syncthreads();

    float sig = 1.f / (1.f + __expf(-presig));
    float kl = key_lengths[b];
    float pa = kl * sig;
    float wv = (float)(*win);
    float std2 = (wv * 0.5f) * (wv * 0.5f);
    float g = __expf(-((kl - pa) * (kl - pa)) / (2.f * std2)) / L;

    const float4* ab = (const float4*)accbuf + (size_t)b * NPART * 256;
    float4 acc = {0.f, 0.f, 0.f, 0.f};
#pragma unroll 8
    for (int i = 0; i < NPART; ++i) {
        float4 v = ab[(size_t)i * 256 + tid];
        float we = cm[192 + i];
        acc.x += we * v.x; acc.y += we * v.y; acc.z += we * v.z; acc.w += we * v.w;
    }
    float4 o = {acc.x * g, acc.y * g, acc.z * g, acc.w * g};
    ((float4*)ctx)[b * 256 + tid] = o;
}

__global__ __launch_bounds__(256, 3) void fused_kernel(const float* __restrict__ query,
                                                       const float* __restrict__ keys,
                                                       const float* __restrict__ Wq,
                                                       const float* __restrict__ wp,
                                                       const float* __restrict__ key_lengths,
                                                       const int* __restrict__ win,
                                                       float* __restrict__ scores,
                                                       float* __restrict__ mlbuf,
                                                       float* __restrict__ accbuf,
                                                       float* __restrict__ gpart,
                                                       int* __restrict__ cnt,
                                                       float* __restrict__ ctx) {
    __shared__ float smem[12288];           // 48 KB: 3 x 16 KB K-tile buffers

    int tid = threadIdx.x;

    if (blockIdx.x < GBLK) {
        // ---- gauss: block g owns u-columns [8g, 8g+8) for ALL 32 b ----
        int g = blockIdx.x;
        int u0 = g * 8;
        float4* s4 = (float4*)smem;
        for (int i = tid; i < 2048; i += 256) {
            int d = i >> 1, h = i & 1;
            s4[i] = *(const float4*)(Wq + (size_t)d * UU + u0 + h * 4);
        }
        __syncthreads();
        int b = tid >> 3, ui = tid & 7;
        const float* qb = query + (size_t)b * DD;
        float acc = 0.f;
#pragma unroll 8
        for (int d = 0; d < DD; ++d) acc += qb[d] * smem[d * 8 + ui];
        float val = tanhf(acc) * wp[u0 + ui];
        val += __shfl_xor(val, 1, 64);
        val += __shfl_xor(val, 2, 64);
        val += __shfl_xor(val, 4, 64);
        if (ui == 0) gpart[b * GBLK + g] = val;

        __threadfence();
        __syncthreads();
        if (tid == 0) {
            unsigned mask = 0;
            for (int b2 = 0; b2 < BB; ++b2) {
                int old = atomicAdd(&cnt[b2], 1);
                if (old == TARGET - 1) mask |= 1u << b2;
            }
            ((unsigned*)smem)[0] = mask;
        }
        __syncthreads();
        unsigned mask = ((unsigned*)smem)[0];
        __syncthreads();
        while (mask) {
            int b2 = __ffs(mask) - 1;
            mask &= mask - 1;
            combine_b(b2, smem, mlbuf, accbuf, gpart, key_lengths, win, ctx, tid);
            __syncthreads();
        }
        return;
    }

    // ---- flash: block = 128-row chunk; wave w owns row (4t + w) of each tile.
    //      3-buffer rotation, 1 barrier/tile, prefetch depth 2, vmcnt(4). ----
    int fb = blockIdx.x - GBLK;
    int b = fb >> 5;               // / CHB
    int chunk = fb & (CHB - 1);
    int s0 = chunk * CHROWS;
    int w = tid >> 6;
    int lane = tid & 63;

    const float4* Q4 = (const float4*)query;
    float4 q0 = Q4[b * 256 + lane],       q1 = Q4[b * 256 + lane + 64],
           q2 = Q4[b * 256 + lane + 128], q3 = Q4[b * 256 + lane + 192];

    const char* gbase = (const char*)(keys + ((size_t)b * SS + s0) * DD);
    float4 a0 = {0,0,0,0}, a1 = {0,0,0,0}, a2 = {0,0,0,0}, a3 = {0,0,0,0};
    float m = -INFINITY, l = 0.f;

    STAGE(0, 0);
    STAGE(1, 1);

    int bf = 0;
    for (int t = 0; t < NT; ++t) {
        if (t + 1 < NT) {
            asm volatile("s_waitcnt vmcnt(4)" ::: "memory");  // tile t landed; t+1 in flight
        } else {
            asm volatile("s_waitcnt vmcnt(0)" ::: "memory");
        }
        __builtin_amdgcn_s_barrier();       // all waves: tile t ready; tile t-1 reads done

        if (t + 2 < NT) {
            int nb = bf + 2; if (nb >= 3) nb -= 3;
            STAGE(t + 2, nb);               // overwrites tile t-1's buffer (safe post-barrier)
        }

        const float* rowp = smem + bf * 4096 + w * 1024;
        float4 k0 = *(const float4*)(rowp + (lane)       * 4);
        float4 k1 = *(const float4*)(rowp + (lane + 64)  * 4);
        float4 k2 = *(const float4*)(rowp + (lane + 128) * 4);
        float4 k3 = *(const float4*)(rowp + (lane + 192) * 4);

        float d = k0.x*q0.x + k0.y*q0.y + k0.z*q0.z + k0.w*q0.w
                + k1.x*q1.x + k1.y*q1.y + k1.z*q1.z + k1.w*q1.w
                + k2.x*q2.x + k2.y*q2.y + k2.z*q2.z + k2.w*q2.w
                + k3.x*q3.x + k3.y*q3.y + k3.z*q3.z + k3.w*q3.w;
#pragma unroll
        for (int o = 32; o > 0; o >>= 1) d += __shfl_xor(d, o, 64);

        if (lane == 0) scores[(size_t)b * SS + s0 + t * TROWS + w] = d;

        float mn = fmaxf(m, d);
        float corr = __expf(m - mn);   // exp(-inf) = 0 handles first tile
        float p = __expf(d - mn);
        l = l * corr + p;
        a0.x = a0.x*corr + p*k0.x; a0.y = a0.y*corr + p*k0.y; a0.z = a0.z*corr + p*k0.z; a0.w = a0.w*corr + p*k0.w;
        a1.x = a1.x*corr + p*k1.x; a1.y = a1.y*corr + p*k1.y; a1.z = a1.z*corr + p*k1.z; a1.w = a1.w*corr + p*k1.w;
        a2.x = a2.x*corr + p*k2.x; a2.y = a2.y*corr + p*k2.y; a2.z = a2.z*corr + p*k2.z; a2.w = a2.w*corr + p*k2.w;
        a3.x = a3.x*corr + p*k3.x; a3.y = a3.y*corr + p*k3.y; a3.z = a3.z*corr + p*k3.z; a3.w = a3.w*corr + p*k3.w;
        m = mn;

        bf += 1; if (bf >= 3) bf -= 3;
    }

    // ---- block-level merge: 4 wave-partials -> 1 block-partial (reuse smem) ----
    __syncthreads();               // all waves done with all tile reads
    if (lane == 0) { smem[8192 + w] = m; smem[8196 + w] = l; }
    __syncthreads();
    float M = fmaxf(fmaxf(smem[8192], smem[8193]), fmaxf(smem[8194], smem[8195]));
    float Ls = smem[8196] * __expf(smem[8192] - M) + smem[8197] * __expf(smem[8193] - M)
             + smem[8198] * __expf(smem[8194] - M) + smem[8199] * __expf(smem[8195] - M);
    float sw = __expf(m - M);
    float4* aw = (float4*)(smem + (size_t)w * 1024);
    float4 t0 = {a0.x*sw, a0.y*sw, a0.z*sw, a0.w*sw};
    float4 t1 = {a1.x*sw, a1.y*sw, a1.z*sw, a1.w*sw};
    float4 t2 = {a2.x*sw, a2.y*sw, a2.z*sw, a2.w*sw};
    float4 t3 = {a3.x*sw, a3.y*sw, a3.z*sw, a3.w*sw};
    __syncthreads();               // ensure M/Ls reads done before overwriting smem
    aw[lane] = t0; aw[lane + 64] = t1; aw[lane + 128] = t2; aw[lane + 192] = t3;
    __syncthreads();
    float4 s = {0,0,0,0};
#pragma unroll
    for (int w2 = 0; w2 < 4; ++w2) {
        float4 v = ((const float4*)(smem + (size_t)w2 * 1024))[tid];
        s.x += v.x; s.y += v.y; s.z += v.z; s.w += v.w;
    }
    ((float4*)(accbuf + (size_t)fb * DD))[tid] = s;
    if (tid == 0) { mlbuf[fb * 2] = M; mlbuf[fb * 2 + 1] = Ls; }

    // ---- arrival: last of 160 contributors for b runs the combine inline ----
    __threadfence();               // all threads: drain own global stores to device scope
    __syncthreads();
    if (tid == 0) {
        int old = atomicAdd(&cnt[b], 1);
        ((int*)smem)[0] = (old == TARGET - 1) ? 1 : 0;
    }
    __syncthreads();
    int doit = ((int*)smem)[0];
    __syncthreads();
    if (doit) combine_b(b, smem, mlbuf, accbuf, gpart, key_lengths, win, ctx, tid);
}

extern "C" void kernel_launch(void* const* d_in, const int* in_sizes, int n_in,
                              void* d_out, int out_size, void* d_ws, size_t ws_size,
                              hipStream_t stream) {
    const float* query       = (const float*)d_in[0];
    const float* keys        = (const float*)d_in[1];
    const float* key_lengths = (const float*)d_in[2];
    const float* Wq          = (const float*)d_in[3];
    const float* wp          = (const float*)d_in[4];
    const int*   win         = (const int*)d_in[5];

    float* out    = (float*)d_out;
    float* ctx    = out;            // B*D floats
    float* scores = out + BB * DD;  // B*S floats
    float* wsbuf  = (float*)d_ws;
    float* gpart  = wsbuf;          // 4096 floats
    float* mlbuf  = wsbuf + 4096;   // FBLK*2 floats
    int*   cnt    = (int*)(wsbuf + 6144);  // 32 ints
    float* accbuf = wsbuf + 8192;   // FBLK*DD floats (4 MiB)

    hipMemsetAsync(cnt, 0, BB * sizeof(int), stream);

    fused_kernel<<<FBLK + GBLK, 256, 0, stream>>>(query, keys, Wq, wp, key_lengths, win,
                                                  scores, mlbuf, accbuf, gpart, cnt, ctx);
}

// Round 12
// 103.126 us; speedup vs baseline: 3.5916x; 3.5916x over previous
//
#include <hip/hip_runtime.h>
#include <math.h>

#define BB 32
#define SS 4096
#define DD 1024
#define UU 1024
#define TROWS 4                 // rows per tile (one per wave)
#define CHROWS 256              // rows per block
#define NT (CHROWS / TROWS)     // 64 tiles per block
#define CHB (SS / CHROWS)       // 16 chunks per batch
#define FBLK (BB * CHB)         // 512 flash blocks
#define GBLK 128                // gauss blocks (u-slices, dispatched first)
#define NPART CHB               // 16 partials per batch (one per block)

#define LOAD_LDS16(g, l) __builtin_amdgcn_global_load_lds( \
    (const __attribute__((address_space(1))) unsigned int*)(g), \
    (__attribute__((address_space(3))) unsigned int*)(l), 16, 0, 0)

// stage one 16 KB tile (4 rows) into LDS buffer `dst` (all 256 threads)
#define STAGE(ti, dst) do {                                              \
    const char* gt_ = gbase + (size_t)(ti) * 16384;                      \
    char* lb_ = (char*)smem + (dst) * 16384;                             \
    _Pragma("unroll")                                                    \
    for (int j_ = 0; j_ < 4; ++j_)                                       \
        LOAD_LDS16(gt_ + j_ * 4096 + tid * 16, lb_ + j_ * 4096 + tid * 16); \
} while (0)

// ws layout (floats):
//   [0 .. 4096)        gpart: per (b, gauss-block) pre-sigmoid partials (b*128+g)
//   [4096 .. 5120)     (m, l) per flash partial (FBLK*2)
//   [8192 .. 8192+FBLK*DD)  acc partials (2 MiB)

__global__ __launch_bounds__(256, 3) void fused_kernel(const float* __restrict__ query,
                                                       const float* __restrict__ keys,
                                                       const float* __restrict__ Wq,
                                                       const float* __restrict__ wp,
                                                       float* __restrict__ scores,
                                                       float* __restrict__ mlbuf,
                                                       float* __restrict__ accbuf,
                                                       float* __restrict__ gpart) {
    __shared__ float smem[12288];           // 48 KB: 3 x 16 KB K-tile buffers

    int tid = threadIdx.x;

    if (blockIdx.x < GBLK) {
        // ---- gauss: block g owns u-columns [8g, 8g+8) for ALL 32 b ----
        int g = blockIdx.x;
        int u0 = g * 8;
        float4* s4 = (float4*)smem;
        for (int i = tid; i < 2048; i += 256) {
            int d = i >> 1, h = i & 1;
            s4[i] = *(const float4*)(Wq + (size_t)d * UU + u0 + h * 4);
        }
        __syncthreads();
        int b = tid >> 3, ui = tid & 7;
        const float* qb = query + (size_t)b * DD;
        float acc = 0.f;
#pragma unroll 8
        for (int d = 0; d < DD; ++d) acc += qb[d] * smem[d * 8 + ui];
        float val = tanhf(acc) * wp[u0 + ui];
        val += __shfl_xor(val, 1, 64);
        val += __shfl_xor(val, 2, 64);
        val += __shfl_xor(val, 4, 64);
        if (ui == 0) gpart[b * GBLK + g] = val;
        return;
    }

    // ---- flash: block = 256-row chunk; wave w owns row (4t + w) of each tile.
    //      3-buffer rotation, 1 barrier/tile, prefetch depth 2, vmcnt(4).
    //      Whole grid (640 blocks) co-resident at 3 blocks/CU: zero dispatch tail. ----
    int fb = blockIdx.x - GBLK;
    int b = fb >> 4;               // / CHB
    int chunk = fb & (CHB - 1);
    int s0 = chunk * CHROWS;
    int w = tid >> 6;
    int lane = tid & 63;

    const float4* Q4 = (const float4*)query;
    float4 q0 = Q4[b * 256 + lane],       q1 = Q4[b * 256 + lane + 64],
           q2 = Q4[b * 256 + lane + 128], q3 = Q4[b * 256 + lane + 192];

    const char* gbase = (const char*)(keys + ((size_t)b * SS + s0) * DD);
    float4 a0 = {0,0,0,0}, a1 = {0,0,0,0}, a2 = {0,0,0,0}, a3 = {0,0,0,0};
    float m = -INFINITY, l = 0.f;

    STAGE(0, 0);
    STAGE(1, 1);

    int bf = 0;
    for (int t = 0; t < NT; ++t) {
        if (t + 1 < NT) {
            asm volatile("s_waitcnt vmcnt(4)" ::: "memory");  // tile t landed; t+1 in flight
        } else {
            asm volatile("s_waitcnt vmcnt(0)" ::: "memory");
        }
        __builtin_amdgcn_s_barrier();       // all waves: tile t ready; tile t-1 reads done

        if (t + 2 < NT) {
            int nb = bf + 2; if (nb >= 3) nb -= 3;
            STAGE(t + 2, nb);               // overwrites tile t-1's buffer (safe post-barrier)
        }

        const float* rowp = smem + bf * 4096 + w * 1024;
        float4 k0 = *(const float4*)(rowp + (lane)       * 4);
        float4 k1 = *(const float4*)(rowp + (lane + 64)  * 4);
        float4 k2 = *(const float4*)(rowp + (lane + 128) * 4);
        float4 k3 = *(const float4*)(rowp + (lane + 192) * 4);

        float d = k0.x*q0.x + k0.y*q0.y + k0.z*q0.z + k0.w*q0.w
                + k1.x*q1.x + k1.y*q1.y + k1.z*q1.z + k1.w*q1.w
                + k2.x*q2.x + k2.y*q2.y + k2.z*q2.z + k2.w*q2.w
                + k3.x*q3.x + k3.y*q3.y + k3.z*q3.z + k3.w*q3.w;
#pragma unroll
        for (int o = 32; o > 0; o >>= 1) d += __shfl_xor(d, o, 64);

        if (lane == 0) scores[(size_t)b * SS + s0 + t * TROWS + w] = d;

        float mn = fmaxf(m, d);
        float corr = __expf(m - mn);   // exp(-inf) = 0 handles first tile
        float p = __expf(d - mn);
        l = l * corr + p;
        a0.x = a0.x*corr + p*k0.x; a0.y = a0.y*corr + p*k0.y; a0.z = a0.z*corr + p*k0.z; a0.w = a0.w*corr + p*k0.w;
        a1.x = a1.x*corr + p*k1.x; a1.y = a1.y*corr + p*k1.y; a1.z = a1.z*corr + p*k1.z; a1.w = a1.w*corr + p*k1.w;
        a2.x = a2.x*corr + p*k2.x; a2.y = a2.y*corr + p*k2.y; a2.z = a2.z*corr + p*k2.z; a2.w = a2.w*corr + p*k2.w;
        a3.x = a3.x*corr + p*k3.x; a3.y = a3.y*corr + p*k3.y; a3.z = a3.z*corr + p*k3.z; a3.w = a3.w*corr + p*k3.w;
        m = mn;

        bf += 1; if (bf >= 3) bf -= 3;
    }

    // ---- block-level merge: 4 wave-partials -> 1 block-partial (reuse smem) ----
    __syncthreads();               // all waves done with all tile reads
    if (lane == 0) { smem[8192 + w] = m; smem[8196 + w] = l; }
    __syncthreads();
    float M = fmaxf(fmaxf(smem[8192], smem[8193]), fmaxf(smem[8194], smem[8195]));
    float Ls = smem[8196] * __expf(smem[8192] - M) + smem[8197] * __expf(smem[8193] - M)
             + smem[8198] * __expf(smem[8194] - M) + smem[8199] * __expf(smem[8195] - M);
    float sw = __expf(m - M);
    float4* aw = (float4*)(smem + (size_t)w * 1024);
    float4 t0 = {a0.x*sw, a0.y*sw, a0.z*sw, a0.w*sw};
    float4 t1 = {a1.x*sw, a1.y*sw, a1.z*sw, a1.w*sw};
    float4 t2 = {a2.x*sw, a2.y*sw, a2.z*sw, a2.w*sw};
    float4 t3 = {a3.x*sw, a3.y*sw, a3.z*sw, a3.w*sw};
    __syncthreads();               // ensure M/Ls reads done before overwriting smem
    aw[lane] = t0; aw[lane + 64] = t1; aw[lane + 128] = t2; aw[lane + 192] = t3;
    __syncthreads();
    float4 s = {0,0,0,0};
#pragma unroll
    for (int w2 = 0; w2 < 4; ++w2) {
        float4 v = ((const float4*)(smem + (size_t)w2 * 1024))[tid];
        s.x += v.x; s.y += v.y; s.z += v.z; s.w += v.w;
    }
    ((float4*)(accbuf + (size_t)fb * DD))[tid] = s;
    if (tid == 0) { mlbuf[fb * 2] = M; mlbuf[fb * 2 + 1] = Ls; }
}

__global__ void combine_kernel(const float* __restrict__ mlbuf,
                               const float* __restrict__ accbuf,
                               const float* __restrict__ gpart,
                               const float* __restrict__ key_lengths,
                               const int* __restrict__ win,
                               float* __restrict__ ctx) {
    int b = blockIdx.x;          // grid (BB, 4)
    int d = blockIdx.y * 256 + threadIdx.x;

    __shared__ float red[128];
    __shared__ float mv[NPART], lv[NPART], wexp[NPART];

    if (threadIdx.x < 128) red[threadIdx.x] = gpart[b * GBLK + threadIdx.x];
    if (threadIdx.x < NPART) {
        mv[threadIdx.x] = mlbuf[(b * NPART + threadIdx.x) * 2];
        lv[threadIdx.x] = mlbuf[(b * NPART + threadIdx.x) * 2 + 1];
    }
    __syncthreads();
    for (int t = 64; t > 0; t >>= 1) {
        if (threadIdx.x < t) red[threadIdx.x] += red[threadIdx.x + t];
        __syncthreads();
    }
    float presig = red[0];

    float M = -INFINITY;
#pragma unroll
    for (int i = 0; i < NPART; ++i) M = fmaxf(M, mv[i]);
    float L = 0.f;
#pragma unroll
    for (int i = 0; i < NPART; ++i) L += lv[i] * __expf(mv[i] - M);
    __syncthreads();
    if (threadIdx.x < NPART) wexp[threadIdx.x] = __expf(mv[threadIdx.x] - M);
    __syncthreads();

    float acc = 0.f;
#pragma unroll 8
    for (int i = 0; i < NPART; ++i)
        acc += wexp[i] * accbuf[((size_t)b * NPART + i) * DD + d];

    float sig = 1.f / (1.f + __expf(-presig));
    float kl = key_lengths[b];
    float pa = kl * sig;
    float wv = (float)(*win);
    float std2 = (wv * 0.5f) * (wv * 0.5f);
    float g = __expf(-((kl - pa) * (kl - pa)) / (2.f * std2));

    ctx[(size_t)b * DD + d] = acc * g / L;
}

extern "C" void kernel_launch(void* const* d_in, const int* in_sizes, int n_in,
                              void* d_out, int out_size, void* d_ws, size_t ws_size,
                              hipStream_t stream) {
    const float* query       = (const float*)d_in[0];
    const float* keys        = (const float*)d_in[1];
    const float* key_lengths = (const float*)d_in[2];
    const float* Wq          = (const float*)d_in[3];
    const float* wp          = (const float*)d_in[4];
    const int*   win         = (const int*)d_in[5];

    float* out    = (float*)d_out;
    float* ctx    = out;            // B*D floats
    float* scores = out + BB * DD;  // B*S floats
    float* wsbuf  = (float*)d_ws;
    float* gpart  = wsbuf;          // 4096 floats
    float* mlbuf  = wsbuf + 4096;   // FBLK*2 floats
    float* accbuf = wsbuf + 8192;   // FBLK*DD floats (2 MiB)

    fused_kernel<<<FBLK + GBLK, 256, 0, stream>>>(query, keys, Wq, wp,
                                                  scores, mlbuf, accbuf, gpart);

    dim3 cgrid(BB, DD / 256);
    combine_kernel<<<cgrid, 256, 0, stream>>>(mlbuf, accbuf, gpart, key_lengths, win, ctx);
}